// Round 5
// baseline (128.891 us; speedup 1.0000x reference)
//
#include <hip/hip_runtime.h>
#include <hip/hip_bf16.h>

typedef __attribute__((ext_vector_type(8))) short bfrag;
typedef __attribute__((ext_vector_type(4))) float facc;
typedef __attribute__((ext_vector_type(4))) int ivec4;
typedef __attribute__((ext_vector_type(4))) short svec4;

#define DIN 195
#define H1 128
#define H2 64
#define CPB 4
#define ROWS 128
#define TPB 512
#define X1STR 136
#define VSTR 72

// d_ws layout (bf16 elems): W1A [3type][2k0][8ht][64lane][8] ; W1C [128h][4] ; W2t [4nt][4k0][64][8]
#define W1A_ELEMS (3*2*8*64*8)   // 24576
#define W1C_ELEMS (128*4)        // 512
#define W2T_ELEMS (4*4*64*8)     // 8192

__device__ __forceinline__ short f2bf(float v) {
    __hip_bfloat16 h = __float2bfloat16(v);
    return __builtin_bit_cast(short, h);
}
__device__ __forceinline__ float celu1(float v) {
    return v > 0.f ? v : (__expf(v) - 1.f);
}

__global__ void prep_weights(const float* __restrict__ W1, const float* __restrict__ W2,
                             __hip_bfloat16* __restrict__ W1A, __hip_bfloat16* __restrict__ W1C,
                             __hip_bfloat16* __restrict__ W2t) {
    int i = blockIdx.x * 256 + threadIdx.x;
    if (i < W1A_ELEMS) {
        int e = i & 7, l = (i >> 3) & 63;
        int ht = (i >> 9) & 7, k0 = (i >> 12) & 1, type = i >> 13;
        int h = ht * 16 + (l & 15);
        int kk = k0 * 32 + ((l >> 4) & 3) * 8 + e;          // 0..63
        int base = (type == 0) ? 3 : (type == 1) ? 67 : 131; // ei | ej | ek blocks
        W1A[i] = __float2bfloat16(W1[h * DIN + base + kk]);
    } else if (i < W1A_ELEMS + W1C_ELEMS) {
        int j = i - W1A_ELEMS;
        int h = j >> 2, q = j & 3;
        float v = (q < 3) ? W1[h * DIN + q] : 0.f;          // dij,dik,djkn weight cols
        W1C[j] = __float2bfloat16(v);
    } else {
        int j = i - W1A_ELEMS - W1C_ELEMS;
        if (j < W2T_ELEMS) {
            int e = j & 7, l = (j >> 3) & 63;
            int k0 = (j >> 9) & 3, nt = j >> 11;
            int h = nt * 16 + (l & 15);
            int k = k0 * 32 + ((l >> 4) & 3) * 8 + e;
            W2t[j] = __float2bfloat16(W2[h * H1 + k]);
        }
    }
}

template<bool PREP>
__global__ __launch_bounds__(TPB, 8) void angnet(
    const float* __restrict__ atoms_xyz,
    const float* __restrict__ embed,
    const float* __restrict__ dist_ij,
    const float* __restrict__ b1,
    const float* __restrict__ b2,
    const int* __restrict__ atype,
    const int* __restrict__ aidx,
    const int* __restrict__ ajdx,
    const __hip_bfloat16* __restrict__ W1A,
    const __hip_bfloat16* __restrict__ W1C,
    const __hip_bfloat16* __restrict__ W2t,
    const float* __restrict__ W1f,
    const float* __restrict__ W2f,
    float* __restrict__ out)
{
    // big union region: x1s[128][136] bf16 (34816 B); bmat[4][128][16] (16384) + smat[128][16] (4096) alias inside
    __shared__ __align__(16) __hip_bfloat16 x1s[ROWS][X1STR];
    __shared__ __align__(16) __hip_bfloat16 vst[CPB][7][VSTR];    // 4032 B: v[c][0..5]=e_n/d_n, [6]=e_i
    __shared__ __align__(16) __hip_bfloat16 tvp[512];             // 1024 B: [0..7]=zero page, later partials
    __shared__ __hip_bfloat16 fcs[ROWS];                          //  256 B
    __shared__ float stg[96];                                     // xyz [c*18+n*3+ax], dist [72+c*6+n]
    __shared__ int   tidxs[28];                                   // [c*7+r]

    __hip_bfloat16 (*bmat)[ROWS][16] = (__hip_bfloat16 (*)[ROWS][16])&x1s[0][0];          // [4][128][16]
    __hip_bfloat16 (*smat)[16]       = (__hip_bfloat16 (*)[16])((char*)&x1s[0][0] + 16384); // [128][16]

    const int tid = threadIdx.x;
    const int C0 = blockIdx.x * CPB;

    // ---- Phase 1: stage indices / xyz / dist, zero the 16B zero-page ----
    if (tid < 28) {
        int c = tid / 7, r = tid % 7;
        tidxs[tid] = (r == 6) ? atype[aidx[C0 + c]] : atype[ajdx[(C0 + c) * 6 + r]];
    } else if (tid >= 32 && tid < 104) {
        int q = tid - 32, c = q / 18, rr = q % 18, n = rr / 3, ax = rr % 3;
        stg[c * 18 + n * 3 + ax] = atoms_xyz[(long)ajdx[(C0 + c) * 6 + n] * 3 + ax];
    } else if (tid >= 104 && tid < 128) {
        int q = tid - 104, c = q / 6, n = q % 6;
        stg[72 + c * 6 + n] = dist_ij[(C0 + c) * 6 + n];
    } else if (tid == 192) {
        ivec4 zz = {0, 0, 0, 0};
        *(ivec4*)&tvp[0] = zz;
    }
    __syncthreads();

    // ---- Phase 2: vst build | smat rows + fcs | bmat w-rows ----
    if (tid < CPB * 7 * 8) {                       // 224: 8 bf16 chunk each
        int c = tid / 56, rem = tid % 56, v = rem / 8, ch = rem % 8;
        int ti = tidxs[c * 7 + v];
        float sc = (v < 6) ? (1.0f / stg[72 + c * 6 + v]) : 1.0f;
        const float* ep = &embed[ti * 64 + ch * 8];
        float4 e0 = *(const float4*)ep;
        float4 e1 = *(const float4*)(ep + 4);
        bfrag t;
        t[0] = f2bf(e0.x * sc); t[1] = f2bf(e0.y * sc);
        t[2] = f2bf(e0.z * sc); t[3] = f2bf(e0.w * sc);
        t[4] = f2bf(e1.x * sc); t[5] = f2bf(e1.y * sc);
        t[6] = f2bf(e1.z * sc); t[7] = f2bf(e1.w * sc);
        *(bfrag*)&vst[c][v][ch * 8] = t;
    } else if (tid >= 256 && tid < 384) {           // 128: one S-row + fc each
        int r = tid - 256;
        int c = r >> 5, t = r & 31;
        ivec4 zz = {0, 0, 0, 0};
        *(ivec4*)&smat[r][0] = zz;
        *(ivec4*)&smat[r][8] = zz;
        if (t < 30) {
            int j = t / 5, k2 = t - j * 5, k = k2 + (k2 >= j ? 1 : 0);
            float dij = stg[72 + c * 6 + j], dik = stg[72 + c * 6 + k];
            float dx = stg[c * 18 + j * 3 + 0] - stg[c * 18 + k * 3 + 0];
            float dy = stg[c * 18 + j * 3 + 1] - stg[c * 18 + k * 3 + 1];
            float dz = stg[c * 18 + j * 3 + 2] - stg[c * 18 + k * 3 + 2];
            float djk = sqrtf(dx * dx + dy * dy + dz * dz);
            float mx = fmaxf(dij, dik), mn = fminf(dij, dik);
            float djkn = (djk - mx + mn) / (2.0f * mn);
            short one = f2bf(1.0f);
            smat[r][0] = __builtin_bit_cast(__hip_bfloat16, one);
            smat[r][1 + j] = __builtin_bit_cast(__hip_bfloat16, one);
            smat[r][7 + k] = __builtin_bit_cast(__hip_bfloat16, one);
            smat[r][13] = __float2bfloat16(dij);
            smat[r][14] = __float2bfloat16(dik);
            smat[r][15] = __float2bfloat16(djkn);
            const float PIF = 3.14159265358979323846f;
            float ca = __cosf(PIF * (dij * (1.0f / 3.5f)));
            float cb = __cosf(PIF * (dik * (1.0f / 3.5f)));
            fcs[r] = __float2bfloat16((0.5f * ca + 0.5f) * (0.5f * cb + 0.5f));
        } else {
            fcs[r] = __float2bfloat16(0.f);
        }
    } else if (tid >= 384 && tid < 512) {           // 128: w-rows (m13..15) for all 4 c
        int h = tid - 384;
        short wv[3];
        if (PREP) {
            svec4 wc = *(const svec4*)&W1C[h * 4];
            wv[0] = wc[0]; wv[1] = wc[1]; wv[2] = wc[2];
        } else {
            wv[0] = f2bf(W1f[h * DIN + 0]);
            wv[1] = f2bf(W1f[h * DIN + 1]);
            wv[2] = f2bf(W1f[h * DIN + 2]);
        }
        #pragma unroll
        for (int c = 0; c < 4; ++c) {
            bmat[c][h][13] = __builtin_bit_cast(__hip_bfloat16, wv[0]);
            bmat[c][h][14] = __builtin_bit_cast(__hip_bfloat16, wv[1]);
            bmat[c][h][15] = __builtin_bit_cast(__hip_bfloat16, wv[2]);
        }
    }
    __syncthreads();

    const int w = tid >> 6, l = tid & 63, lr = l & 15, lq = l >> 4;

    // ================= GEMM1a: U,P,Q matvecs; wave w owns h-tile w =================
    {
        // A-frag vst byte-offsets (bf16 idx) per lane row lr
        int rU = (lr < 4) ? lr : 0;
        int offU = (rU * 7 + 6) * VSTR;
        int cP0 = lr / 6, vP0 = lr - cP0 * 6;
        int offP0 = (cP0 * 7 + vP0) * VSTR;
        int r1 = 16 + lr; if (r1 > 23) r1 = 23;
        int cP1 = r1 / 6, vP1 = r1 - cP1 * 6;
        int offP1 = (cP1 * 7 + vP1) * VSTR;

        facc accU = {0,0,0,0}, accP0 = {0,0,0,0}, accP1 = {0,0,0,0}, accQ0 = {0,0,0,0}, accQ1 = {0,0,0,0};
        #pragma unroll
        for (int k0 = 0; k0 < 2; ++k0) {
            int ko = k0 * 32 + lq * 8;
            bfrag fU  = *(const bfrag*)&((__hip_bfloat16*)vst)[offU + ko];
            bfrag fP0 = *(const bfrag*)&((__hip_bfloat16*)vst)[offP0 + ko];
            bfrag fP1 = *(const bfrag*)&((__hip_bfloat16*)vst)[offP1 + ko];
            bfrag Wei, Wej, Wek;
            if (PREP) {
                Wei = *(const bfrag*)&W1A[((0 * 2 + k0) * 8 + w) * 512 + l * 8];
                Wej = *(const bfrag*)&W1A[((1 * 2 + k0) * 8 + w) * 512 + l * 8];
                Wek = *(const bfrag*)&W1A[((2 * 2 + k0) * 8 + w) * 512 + l * 8];
            } else {
                int h = w * 16 + lr;
                #pragma unroll
                for (int e = 0; e < 8; ++e) {
                    int kk = k0 * 32 + lq * 8 + e;
                    Wei[e] = f2bf(W1f[h * DIN + 3 + kk]);
                    Wej[e] = f2bf(W1f[h * DIN + 67 + kk]);
                    Wek[e] = f2bf(W1f[h * DIN + 131 + kk]);
                }
            }
            accU  = __builtin_amdgcn_mfma_f32_16x16x32_bf16(fU,  Wei, accU,  0, 0, 0);
            accP0 = __builtin_amdgcn_mfma_f32_16x16x32_bf16(fP0, Wej, accP0, 0, 0, 0);
            accP1 = __builtin_amdgcn_mfma_f32_16x16x32_bf16(fP1, Wej, accP1, 0, 0, 0);
            accQ0 = __builtin_amdgcn_mfma_f32_16x16x32_bf16(fP0, Wek, accQ0, 0, 0, 0);
            accQ1 = __builtin_amdgcn_mfma_f32_16x16x32_bf16(fP1, Wek, accQ1, 0, 0, 0);
        }

        // epilogue-1a: D rows m = lq*4+g, col h = w*16+lr -> bmat slots
        int h = w * 16 + lr;
        if (lq == 0) {
            float b1v = b1[h];
            #pragma unroll
            for (int g = 0; g < 4; ++g)
                bmat[g][h][0] = __float2bfloat16(accU[g] + b1v);  // U + b1, c = g
        }
        #pragma unroll
        for (int g = 0; g < 4; ++g) {
            int row = lq * 4 + g;                 // 0..15 -> P/Q rows
            int cg = row / 6, ng = row - cg * 6;
            bmat[cg][h][1 + ng] = __float2bfloat16(accP0[g]);
            bmat[cg][h][7 + ng] = __float2bfloat16(accQ0[g]);
            int row1 = 16 + row;                  // 16..31, valid < 24
            if (row1 < 24) {
                int c1 = row1 / 6, n1 = row1 - c1 * 6;
                bmat[c1][h][1 + n1] = __float2bfloat16(accP1[g]);
                bmat[c1][h][7 + n1] = __float2bfloat16(accQ1[g]);
            }
        }
    }
    __syncthreads();

    // ================= GEMM1b: x1pre[h][r] = bmat[c] (h x m) @ S^T (m x r) =================
    facc a1[8];
    #pragma unroll
    for (int n = 0; n < 8; ++n) a1[n] = (facc){0.f, 0.f, 0.f, 0.f};
    {
        const int cw = w >> 1;
        const int r = w * 16 + lr;
        const __hip_bfloat16* zp = &tvp[0];
        // B-frag: S[r][m], K zero-padded (lq>=2 -> zero page)
        const __hip_bfloat16* sp = (lq < 2) ? &smat[r][lq * 8] : zp;
        bfrag Sf = *(const bfrag*)sp;
        #pragma unroll
        for (int n = 0; n < 8; ++n) {
            int h = n * 16 + lr;
            const __hip_bfloat16* ap = (lq < 2) ? &bmat[cw][h][lq * 8] : zp;
            bfrag Af = *(const bfrag*)ap;
            a1[n] = __builtin_amdgcn_mfma_f32_16x16x32_bf16(Af, Sf, a1[n], 0, 0, 0);
        }
    }
    __syncthreads();   // all bmat/smat reads done before x1s overwrite

    // ---- Epilogue 1: celu -> x1s[r][h] (4 contiguous h per n-tile) ----
    {
        const int r = w * 16 + lr;
        #pragma unroll
        for (int n = 0; n < 8; ++n) {
            svec4 pk;
            #pragma unroll
            for (int g = 0; g < 4; ++g) pk[g] = f2bf(celu1(a1[n][g]));
            *(svec4*)&x1s[r][n * 16 + lq * 4] = pk;
        }
    }
    __syncthreads();

    // ================= GEMM2: D2[r][o]; wave w owns r-tile w, all 64 o =================
    facc a2[4];
    #pragma unroll
    for (int n = 0; n < 4; ++n) a2[n] = (facc){0.f, 0.f, 0.f, 0.f};

    #pragma unroll
    for (int k0 = 0; k0 < 4; ++k0) {
        bfrag Af2 = *(const bfrag*)&x1s[w * 16 + lr][k0 * 32 + lq * 8];
        #pragma unroll
        for (int n = 0; n < 4; ++n) {
            bfrag Bf2;
            if (PREP) {
                Bf2 = *(const bfrag*)&W2t[(n * 4 + k0) * 512 + l * 8];
            } else {
                #pragma unroll
                for (int e = 0; e < 8; ++e)
                    Bf2[e] = f2bf(W2f[(n * 16 + lr) * H1 + k0 * 32 + lq * 8 + e]);
            }
            a2[n] = __builtin_amdgcn_mfma_f32_16x16x32_bf16(Af2, Bf2, a2[n], 0, 0, 0);
        }
    }

    // ---- Epilogue 2: celu + fc, local g-sum + 2 shfls -> bf16 partials ----
    {
        float fr[4];
        #pragma unroll
        for (int g = 0; g < 4; ++g) fr[g] = __bfloat162float(fcs[w * 16 + lq * 4 + g]);
        float t[4];
        #pragma unroll
        for (int n = 0; n < 4; ++n) {
            float b2v = b2[n * 16 + lr];
            float s = 0.f;
            #pragma unroll
            for (int g = 0; g < 4; ++g)
                s += celu1(a2[n][g] + b2v) * fr[g];
            s += __shfl_xor(s, 16);
            s += __shfl_xor(s, 32);
            t[n] = s;
        }
        if (lq == 0) {
            #pragma unroll
            for (int n = 0; n < 4; ++n)
                tvp[w * 64 + n * 16 + lr] = __float2bfloat16(t[n]);
        }
    }
    __syncthreads();

    // ---- Final: combine two half-center partials, coalesced store ----
    if (tid < 256) {
        int c = tid >> 6, o = tid & 63;
        out[(long)(C0 + c) * 64 + o] =
            __bfloat162float(tvp[(2 * c) * 64 + o]) + __bfloat162float(tvp[(2 * c + 1) * 64 + o]);
    }
}

extern "C" void kernel_launch(void* const* d_in, const int* in_sizes, int n_in,
                              void* d_out, int out_size, void* d_ws, size_t ws_size,
                              hipStream_t stream) {
    const float* atoms_xyz = (const float*)d_in[0];
    const float* embed     = (const float*)d_in[1];
    const float* dist_ij   = (const float*)d_in[2];
    const float* W1        = (const float*)d_in[3];
    const float* b1        = (const float*)d_in[4];
    const float* W2        = (const float*)d_in[5];
    const float* b2        = (const float*)d_in[6];
    const int*   atype     = (const int*)d_in[7];
    const int*   aidx      = (const int*)d_in[8];
    const int*   ajdx      = (const int*)d_in[9];
    float* out = (float*)d_out;

    const int n_center = in_sizes[8];            // 40000
    const int n_blocks = n_center / CPB;         // 10000

    size_t need = (size_t)(W1A_ELEMS + W1C_ELEMS + W2T_ELEMS) * sizeof(__hip_bfloat16);
    if (ws_size >= need) {
        __hip_bfloat16* W1Ap = (__hip_bfloat16*)d_ws;
        __hip_bfloat16* W1Cp = W1Ap + W1A_ELEMS;
        __hip_bfloat16* W2tp = W1Cp + W1C_ELEMS;
        int prep_total = W1A_ELEMS + W1C_ELEMS + W2T_ELEMS;
        prep_weights<<<(prep_total + 255) / 256, 256, 0, stream>>>(W1, W2, W1Ap, W1Cp, W2tp);
        angnet<true><<<n_blocks, TPB, 0, stream>>>(atoms_xyz, embed, dist_ij, b1, b2,
                                                   atype, aidx, ajdx, W1Ap, W1Cp, W2tp, W1, W2, out);
    } else {
        angnet<false><<<n_blocks, TPB, 0, stream>>>(atoms_xyz, embed, dist_ij, b1, b2,
                                                    atype, aidx, ajdx, nullptr, nullptr, nullptr, W1, W2, out);
    }
}

// Round 6
// 120.019 us; speedup vs baseline: 1.0739x; 1.0739x over previous
//
#include <hip/hip_runtime.h>
#include <hip/hip_bf16.h>

typedef __attribute__((ext_vector_type(8))) short bfrag;
typedef __attribute__((ext_vector_type(4))) float facc;
typedef __attribute__((ext_vector_type(4))) int ivec4;
typedef __attribute__((ext_vector_type(2))) int ivec2;
typedef __attribute__((ext_vector_type(4))) short svec4;

#define DIN 195
#define H1 128
#define H2 64
#define CPB 4
#define ROWS 128
#define TPB 512
#define X1STR 136
#define VSTR 72

#define W1T_ELEMS (8*7*64*8)   // [mtile][k0][lane][8]
#define W2T_ELEMS (4*4*64*8)   // [ntile][k0][lane][8]

__device__ __forceinline__ short f2bf(float v) {
    __hip_bfloat16 h = __float2bfloat16(v);
    return __builtin_bit_cast(short, h);
}
__device__ __forceinline__ float celu1(float v) {
    return v > 0.f ? v : (__expf(v) - 1.f);
}

// W1t: A-fragment order. Column permutation: kp<192 -> orig 3+kp (ei|ej|ek),
// kp 192..194 -> orig 0..2 (dij,dik,djkn), kp==195 -> b1 (bias column), else 0.
__global__ void prep_weights(const float* __restrict__ W1, const float* __restrict__ W2,
                             const float* __restrict__ b1,
                             __hip_bfloat16* __restrict__ W1t, __hip_bfloat16* __restrict__ W2t) {
    int i = blockIdx.x * 256 + threadIdx.x;
    if (i < W1T_ELEMS) {
        int e = i & 7, l = (i >> 3) & 63;
        int k0 = (i >> 9) % 7, mt = (i >> 9) / 7;
        int h = mt * 16 + (l & 15);
        int kp = k0 * 32 + ((l >> 4) & 3) * 8 + e;
        float v = 0.f;
        if (kp < 192)       v = W1[h * DIN + 3 + kp];
        else if (kp < 195)  v = W1[h * DIN + (kp - 192)];
        else if (kp == 195) v = b1[h];
        W1t[i] = __float2bfloat16(v);
    } else {
        int j = i - W1T_ELEMS;
        if (j < W2T_ELEMS) {
            int e = j & 7, l = (j >> 3) & 63;
            int k0 = (j >> 9) & 3, nt = j >> 11;
            int h = nt * 16 + (l & 15);
            int k = k0 * 32 + ((l >> 4) & 3) * 8 + e;
            W2t[j] = __float2bfloat16(W2[h * H1 + k]);
        }
    }
}

template<bool PREP>
__global__ __launch_bounds__(TPB, 6) void angnet(
    const float* __restrict__ atoms_xyz,
    const float* __restrict__ embed,
    const float* __restrict__ dist_ij,
    const float* __restrict__ b1,
    const float* __restrict__ b2,
    const int* __restrict__ atype,
    const int* __restrict__ aidx,
    const int* __restrict__ ajdx,
    const __hip_bfloat16* __restrict__ W1t,
    const __hip_bfloat16* __restrict__ W2t,
    const float* __restrict__ W1f,
    const float* __restrict__ W2f,
    float* __restrict__ out)
{
    __shared__ __align__(16) __hip_bfloat16 x1s[ROWS][X1STR];     // 34816 B (staging aliased at start)
    __shared__ __align__(16) __hip_bfloat16 vst[CPB][7][VSTR];    //  4032 B
    __shared__ __align__(16) __hip_bfloat16 tvp[512];             //  1024 B: tailv[128][4] then partials[8][64]
    __shared__ __hip_bfloat16 fcs[ROWS];                          //   256 B

    // staging aliased into x1s (dead once epilogue-1 writes x1s)
    float* stg  = (float*)&x1s[0][0];      // [0..71] xyzs(c,n,ax)=stg[c*18+n*3+ax]; [72..95] dstage(c,n)=stg[72+c*6+n]
    int*   tidxp = (int*)(stg + 96);       // [0..27] tidx(c,r)

    const int tid = threadIdx.x;
    const int C0 = blockIdx.x * CPB;
    const int w = tid >> 6, l = tid & 63, lr = l & 15, lq = l >> 4;

    // ---- Prefetch all 7 W1t A-fragments (independent of LDS phases; hides HBM/L2 latency) ----
    bfrag W1fr[7];
    if (PREP) {
        #pragma unroll
        for (int k0 = 0; k0 < 7; ++k0)
            W1fr[k0] = *(const bfrag*)&W1t[(w * 7 + k0) * 512 + l * 8];
    }

    // ---- Phase 1: zero tailv, stage indices / xyz / dist ----
    if (tid < 64) {
        ivec4 zz = {0, 0, 0, 0};
        ((ivec4*)tvp)[tid] = zz;
    } else if (tid >= 64 && tid < 92) {
        int q = tid - 64, c = q / 7, r = q % 7;
        tidxp[c * 7 + r] = (r == 6) ? atype[aidx[C0 + c]] : atype[ajdx[(C0 + c) * 6 + r]];
    } else if (tid >= 96 && tid < 168) {
        int q = tid - 96, c = q / 18, rr = q % 18, n = rr / 3, ax = rr % 3;
        stg[c * 18 + n * 3 + ax] = atoms_xyz[(long)ajdx[(C0 + c) * 6 + n] * 3 + ax];
    } else if (tid >= 168 && tid < 192) {
        int q = tid - 168, c = q / 6, n = q % 6;
        stg[72 + c * 6 + n] = dist_ij[(C0 + c) * 6 + n];
    }
    __syncthreads();

    // ---- Phase 2: build vst (7 distinct 64-vectors per center) + per-row scalars ----
    if (tid < CPB * 7 * 8) {
        int c = tid / 56, rem = tid % 56, v = rem / 8, ch = rem % 8;
        int ti = tidxp[c * 7 + v];
        float sc = (v < 6) ? (1.0f / stg[72 + c * 6 + v]) : 1.0f;
        const float* ep = &embed[ti * 64 + ch * 8];
        float4 e0 = *(const float4*)ep;
        float4 e1 = *(const float4*)(ep + 4);
        bfrag t;
        t[0] = f2bf(e0.x * sc); t[1] = f2bf(e0.y * sc);
        t[2] = f2bf(e0.z * sc); t[3] = f2bf(e0.w * sc);
        t[4] = f2bf(e1.x * sc); t[5] = f2bf(e1.y * sc);
        t[6] = f2bf(e1.z * sc); t[7] = f2bf(e1.w * sc);
        *(bfrag*)&vst[c][v][ch * 8] = t;
    } else if (tid >= 256 && tid < 256 + CPB * 30) {
        int q = tid - 256, c = q / 30, t = q % 30;
        int j = t / 5, k2 = t - j * 5, k = k2 + (k2 >= j ? 1 : 0);
        float dij = stg[72 + c * 6 + j], dik = stg[72 + c * 6 + k];
        float dx = stg[c * 18 + j * 3 + 0] - stg[c * 18 + k * 3 + 0];
        float dy = stg[c * 18 + j * 3 + 1] - stg[c * 18 + k * 3 + 1];
        float dz = stg[c * 18 + j * 3 + 2] - stg[c * 18 + k * 3 + 2];
        float djk = sqrtf(dx * dx + dy * dy + dz * dz);
        float mx = fmaxf(dij, dik), mn = fminf(dij, dik);
        float djkn = (djk - mx + mn) / (2.0f * mn);
        int r = c * 32 + t;
        svec4 pk;
        pk[0] = f2bf(dij); pk[1] = f2bf(dik); pk[2] = f2bf(djkn); pk[3] = f2bf(1.0f);
        *(svec4*)&tvp[r * 4] = pk;
        const float PIF = 3.14159265358979323846f;
        float ca = __cosf(PIF * (dij * (1.0f / 3.5f)));
        float cb = __cosf(PIF * (dik * (1.0f / 3.5f)));
        fcs[r] = __float2bfloat16((0.5f * ca + 0.5f) * (0.5f * cb + 0.5f));
    } else if (tid >= 376 && tid < 384) {
        int p = tid - 376;
        fcs[(p >> 1) * 32 + 30 + (p & 1)] = __float2bfloat16(0.f);
    }
    __syncthreads();

    // ---- GEMM1: D1[h][r], wave w owns h in [16w,16w+16), all 128 r ----
    // per-thread loop-invariant B addressing
    int jA = lr / 5, k2A = lr % 5; int kA = k2A + (k2A >= jA ? 1 : 0);
    int tB = 16 + lr, jB = 0, kB = 0;
    if (tB < 30) { jB = tB / 5; int k2B = tB % 5; kB = k2B + (k2B >= jB ? 1 : 0); }
    const int joA = jA * VSTR, joB = jB * VSTR, koA = kA * VSTR, koB = kB * VSTR;
    const __hip_bfloat16* vb[4];
    #pragma unroll
    for (int c = 0; c < 4; ++c) vb[c] = &vst[c][0][lq * 8];

    facc a1[8];
    #pragma unroll
    for (int n = 0; n < 8; ++n) a1[n] = (facc){0.f, 0.f, 0.f, 0.f};

    #pragma unroll
    for (int k0 = 0; k0 < 7; ++k0) {
        bfrag Af;
        if (PREP) {
            Af = W1fr[k0];
        } else {
            #pragma unroll
            for (int e = 0; e < 8; ++e) {
                int kp = k0 * 32 + lq * 8 + e;
                int h = w * 16 + lr;
                float v = 0.f;
                if (kp < 192)       v = W1f[h * DIN + 3 + kp];
                else if (kp < 195)  v = W1f[h * DIN + kp - 192];
                else if (kp == 195) v = b1[h];
                Af[e] = f2bf(v);
            }
        }
        #pragma unroll
        for (int n = 0; n < 8; ++n) {
            bfrag Bf;
            if (k0 < 6) {
                const __hip_bfloat16* bp;
                if (k0 < 2)      bp = vb[n >> 1] + 6 * VSTR + (k0 & 1) * 32;
                else if (k0 < 4) bp = vb[n >> 1] + ((n & 1) ? joB : joA) + (k0 & 1) * 32;
                else             bp = vb[n >> 1] + ((n & 1) ? koB : koA) + (k0 & 1) * 32;
                Bf = *(const bfrag*)bp;
            } else {
                // tail tile: only lq==0 lanes carry data (kp 192..199), rest zero
                svec4 tv = *(const svec4*)&tvp[(n * 16 + lr) * 4];
                ivec2 ti = __builtin_bit_cast(ivec2, tv);
                int lo = (lq == 0) ? ti[0] : 0;
                int hi = (lq == 0) ? ti[1] : 0;
                ivec4 bi = {lo, hi, 0, 0};
                Bf = __builtin_bit_cast(bfrag, bi);
            }
            a1[n] = __builtin_amdgcn_mfma_f32_16x16x32_bf16(Af, Bf, a1[n], 0, 0, 0);
        }
    }

    // ---- Prefetch W2t k0=0,1 (global, independent of the upcoming LDS barrier) ----
    bfrag W2fr0[4], W2fr1[4];
    if (PREP) {
        #pragma unroll
        for (int n = 0; n < 4; ++n) W2fr0[n] = *(const bfrag*)&W2t[(n * 4 + 0) * 512 + l * 8];
        #pragma unroll
        for (int n = 0; n < 4; ++n) W2fr1[n] = *(const bfrag*)&W2t[(n * 4 + 1) * 512 + l * 8];
    }

    // ---- Epilogue 1: celu -> x1s (bias folded into GEMM1) ----
    #pragma unroll
    for (int n = 0; n < 8; ++n) {
        svec4 pk;
        #pragma unroll
        for (int g = 0; g < 4; ++g) pk[g] = f2bf(celu1(a1[n][g]));
        *(svec4*)&x1s[n * 16 + lr][w * 16 + lq * 4] = pk;
    }
    __syncthreads();

    // ---- GEMM2: D2[r][o]; wave w owns rows [16w,16w+16), all 64 o ----
    // issue remaining W2t loads + b2 immediately so latency hides under k0=0,1 compute
    bfrag W2fr2[4], W2fr3[4];
    if (PREP) {
        #pragma unroll
        for (int n = 0; n < 4; ++n) W2fr2[n] = *(const bfrag*)&W2t[(n * 4 + 2) * 512 + l * 8];
        #pragma unroll
        for (int n = 0; n < 4; ++n) W2fr3[n] = *(const bfrag*)&W2t[(n * 4 + 3) * 512 + l * 8];
    }
    float b2v[4];
    #pragma unroll
    for (int n = 0; n < 4; ++n) b2v[n] = b2[n * 16 + lr];

    facc a2[4];
    #pragma unroll
    for (int n = 0; n < 4; ++n) a2[n] = (facc){0.f, 0.f, 0.f, 0.f};

    #pragma unroll
    for (int k0 = 0; k0 < 4; ++k0) {
        bfrag Af2 = *(const bfrag*)&x1s[w * 16 + lr][k0 * 32 + lq * 8];
        #pragma unroll
        for (int n = 0; n < 4; ++n) {
            bfrag Bf2;
            if (PREP) {
                Bf2 = (k0 == 0) ? W2fr0[n] : (k0 == 1) ? W2fr1[n] : (k0 == 2) ? W2fr2[n] : W2fr3[n];
            } else {
                #pragma unroll
                for (int e = 0; e < 8; ++e)
                    Bf2[e] = f2bf(W2f[(n * 16 + lr) * H1 + k0 * 32 + lq * 8 + e]);
            }
            a2[n] = __builtin_amdgcn_mfma_f32_16x16x32_bf16(Af2, Bf2, a2[n], 0, 0, 0);
        }
    }

    // ---- Epilogue 2: celu + fc, g-sum + 2 shfls, bf16 partials ----
    {
        float fr[4];
        #pragma unroll
        for (int g = 0; g < 4; ++g) fr[g] = __bfloat162float(fcs[w * 16 + lq * 4 + g]);
        float t[4];
        #pragma unroll
        for (int n = 0; n < 4; ++n) {
            float s = 0.f;
            #pragma unroll
            for (int g = 0; g < 4; ++g)
                s += celu1(a2[n][g] + b2v[n]) * fr[g];
            s += __shfl_xor(s, 16);
            s += __shfl_xor(s, 32);
            t[n] = s;
        }
        if (lq == 0) {
            #pragma unroll
            for (int n = 0; n < 4; ++n)
                tvp[w * 64 + n * 16 + lr] = __float2bfloat16(t[n]);
        }
    }
    __syncthreads();

    // ---- Final: combine the two half-center partials, coalesced store ----
    if (tid < 256) {
        int c = tid >> 6, o = tid & 63;
        out[(long)(C0 + c) * 64 + o] =
            __bfloat162float(tvp[(2 * c) * 64 + o]) + __bfloat162float(tvp[(2 * c + 1) * 64 + o]);
    }
}

extern "C" void kernel_launch(void* const* d_in, const int* in_sizes, int n_in,
                              void* d_out, int out_size, void* d_ws, size_t ws_size,
                              hipStream_t stream) {
    const float* atoms_xyz = (const float*)d_in[0];
    const float* embed     = (const float*)d_in[1];
    const float* dist_ij   = (const float*)d_in[2];
    const float* W1        = (const float*)d_in[3];
    const float* b1        = (const float*)d_in[4];
    const float* W2        = (const float*)d_in[5];
    const float* b2        = (const float*)d_in[6];
    const int*   atype     = (const int*)d_in[7];
    const int*   aidx      = (const int*)d_in[8];
    const int*   ajdx      = (const int*)d_in[9];
    float* out = (float*)d_out;

    const int n_center = in_sizes[8];            // 40000
    const int n_blocks = n_center / CPB;         // 10000

    size_t need = (size_t)(W1T_ELEMS + W2T_ELEMS) * sizeof(__hip_bfloat16);
    if (ws_size >= need) {
        __hip_bfloat16* W1t = (__hip_bfloat16*)d_ws;
        __hip_bfloat16* W2t = W1t + W1T_ELEMS;
        int prep_total = W1T_ELEMS + W2T_ELEMS;
        prep_weights<<<(prep_total + 255) / 256, 256, 0, stream>>>(W1, W2, b1, W1t, W2t);
        angnet<true><<<n_blocks, TPB, 0, stream>>>(atoms_xyz, embed, dist_ij, b1, b2,
                                                   atype, aidx, ajdx, W1t, W2t, W1, W2, out);
    } else {
        angnet<false><<<n_blocks, TPB, 0, stream>>>(atoms_xyz, embed, dist_ij, b1, b2,
                                                    atype, aidx, ajdx, nullptr, nullptr, W1, W2, out);
    }
}